// Round 1
// 8111.906 us; speedup vs baseline: 1.1301x; 1.1301x over previous
//
#include <hip/hip_runtime.h>
#include <math.h>

#define DMODEL 512
#define NHEAD  8
#define DHEAD  64
#define SEQ    512
#define BATCH  4
#define NLAYER 6
#define FFDIM  2048
#define VOCAB  32000
#define TK 16

// ---------------------------------------------------------------------------
// Embedding * sqrt(D) + sinusoidal positional encoding
// ---------------------------------------------------------------------------
__global__ void embed_kernel(const int* __restrict__ tokens,
                             const float* __restrict__ emb,
                             float* __restrict__ x) {
    int idx = blockIdx.x;              // b*S + s
    int s   = idx & (SEQ - 1);
    int tok = tokens[idx];
    const float scale = 22.627416997969522f;  // sqrt(512)
    for (int d = threadIdx.x; d < DMODEL; d += blockDim.x) {
        float i2  = (float)((d >> 1) << 1) / (float)DMODEL;
        float inv = powf(10000.0f, -i2);
        float em  = (float)s * inv;
        float pe  = ((d & 1) == 0) ? sinf(em) : cosf(em);
        x[(size_t)idx * DMODEL + d] = emb[(size_t)tok * DMODEL + d] * scale + pe;
    }
}

// ---------------------------------------------------------------------------
// GEMM  C[m,n] = sum_k A[m,k]*W[n,k] + bias[n]  (optional ReLU)
// A:[M,K] row-major, W:[N,K] row-major (torch [out,in]).
//
// gemm_bias_64 : 64x64 tile, TK=16, 256 thr, 4x4 micro. LDS transposed
//                [k][row] so fragments are ds_read_b128. Used for N-small
//                shapes where grid>=256 blocks matters.
// gemm_bias_128: 128x128 tile, 8x8 micro (split 4+4). Used for FF1 + vocab.
// Both software-pipeline the global->reg prefetch across the K loop.
// Requires M%tile==0, N%tile==0, K%16==0 (true for all shapes here).
// ---------------------------------------------------------------------------
__global__ __launch_bounds__(256) void gemm_bias_64(
        const float* __restrict__ A, const float* __restrict__ W,
        const float* __restrict__ bias, float* __restrict__ C,
        int M, int N, int K, int relu) {
    __shared__ float As[TK][64 + 4];   // [k][row], pad keeps writes 2-way max
    __shared__ float Bs[TK][64 + 4];
    int bm  = blockIdx.y * 64;
    int bn  = blockIdx.x * 64;
    int tid = threadIdx.x;
    int tx  = tid & 15;                // col micro
    int ty  = tid >> 4;                // row micro
    int lrow = tid >> 2;               // 0..63 staging row
    int lq   = (tid & 3) << 2;         // k-quad 0,4,8,12

    const float* Ap = A + (size_t)(bm + lrow) * K + lq;
    const float* Wp = W + (size_t)(bn + lrow) * K + lq;

    float acc[4][4] = {};
    float4 av = *(const float4*)Ap;
    float4 wv = *(const float4*)Wp;

    for (int k0 = 0; k0 < K; k0 += TK) {
        As[lq + 0][lrow] = av.x; As[lq + 1][lrow] = av.y;
        As[lq + 2][lrow] = av.z; As[lq + 3][lrow] = av.w;
        Bs[lq + 0][lrow] = wv.x; Bs[lq + 1][lrow] = wv.y;
        Bs[lq + 2][lrow] = wv.z; Bs[lq + 3][lrow] = wv.w;
        __syncthreads();
        int kn = (k0 + TK < K) ? k0 + TK : k0;   // redundant last load, in-bounds
        av = *(const float4*)(Ap + kn);
        wv = *(const float4*)(Wp + kn);
#pragma unroll
        for (int kk = 0; kk < TK; kk++) {
            float4 a = *(const float4*)&As[kk][ty * 4];   // broadcast, free
            float4 b = *(const float4*)&Bs[kk][tx * 4];   // 2-way, free
            float ar[4] = {a.x, a.y, a.z, a.w};
            float br[4] = {b.x, b.y, b.z, b.w};
#pragma unroll
            for (int i = 0; i < 4; i++)
#pragma unroll
                for (int j = 0; j < 4; j++) acc[i][j] += ar[i] * br[j];
        }
        __syncthreads();
    }

    float4 bv = *(const float4*)(bias + bn + tx * 4);
    float bb[4] = {bv.x, bv.y, bv.z, bv.w};
#pragma unroll
    for (int i = 0; i < 4; i++) {
        int row = bm + ty * 4 + i;
        float4 v;
        v.x = acc[i][0] + bb[0]; v.y = acc[i][1] + bb[1];
        v.z = acc[i][2] + bb[2]; v.w = acc[i][3] + bb[3];
        if (relu) {
            v.x = fmaxf(v.x, 0.f); v.y = fmaxf(v.y, 0.f);
            v.z = fmaxf(v.z, 0.f); v.w = fmaxf(v.w, 0.f);
        }
        *(float4*)(C + (size_t)row * N + bn + tx * 4) = v;
    }
}

__global__ __launch_bounds__(256) void gemm_bias_128(
        const float* __restrict__ A, const float* __restrict__ W,
        const float* __restrict__ bias, float* __restrict__ C,
        int M, int N, int K, int relu) {
    __shared__ float As[TK][128 + 4];
    __shared__ float Bs[TK][128 + 4];
    int bm  = blockIdx.y * 128;
    int bn  = blockIdx.x * 128;
    int tid = threadIdx.x;
    int tx  = tid & 15;                // cols tx*4..+3 and +64
    int ty  = tid >> 4;                // rows ty*4..+3 and +64
    int lrow = tid >> 2;               // 0..63 (and +64)
    int lq   = (tid & 3) << 2;

    const float* Ap  = A + (size_t)(bm + lrow) * K + lq;
    const float* Ap2 = Ap + (size_t)64 * K;
    const float* Wp  = W + (size_t)(bn + lrow) * K + lq;
    const float* Wp2 = Wp + (size_t)64 * K;

    float acc[8][8] = {};
    float4 a0 = *(const float4*)Ap;
    float4 a1 = *(const float4*)Ap2;
    float4 w0 = *(const float4*)Wp;
    float4 w1 = *(const float4*)Wp2;

    for (int k0 = 0; k0 < K; k0 += TK) {
        As[lq + 0][lrow]      = a0.x; As[lq + 1][lrow]      = a0.y;
        As[lq + 2][lrow]      = a0.z; As[lq + 3][lrow]      = a0.w;
        As[lq + 0][lrow + 64] = a1.x; As[lq + 1][lrow + 64] = a1.y;
        As[lq + 2][lrow + 64] = a1.z; As[lq + 3][lrow + 64] = a1.w;
        Bs[lq + 0][lrow]      = w0.x; Bs[lq + 1][lrow]      = w0.y;
        Bs[lq + 2][lrow]      = w0.z; Bs[lq + 3][lrow]      = w0.w;
        Bs[lq + 0][lrow + 64] = w1.x; Bs[lq + 1][lrow + 64] = w1.y;
        Bs[lq + 2][lrow + 64] = w1.z; Bs[lq + 3][lrow + 64] = w1.w;
        __syncthreads();
        int kn = (k0 + TK < K) ? k0 + TK : k0;
        a0 = *(const float4*)(Ap + kn);
        a1 = *(const float4*)(Ap2 + kn);
        w0 = *(const float4*)(Wp + kn);
        w1 = *(const float4*)(Wp2 + kn);
#pragma unroll
        for (int kk = 0; kk < TK; kk++) {
            float4 A0 = *(const float4*)&As[kk][ty * 4];
            float4 A1 = *(const float4*)&As[kk][ty * 4 + 64];
            float4 B0 = *(const float4*)&Bs[kk][tx * 4];
            float4 B1 = *(const float4*)&Bs[kk][tx * 4 + 64];
            float ar[8] = {A0.x, A0.y, A0.z, A0.w, A1.x, A1.y, A1.z, A1.w};
            float br[8] = {B0.x, B0.y, B0.z, B0.w, B1.x, B1.y, B1.z, B1.w};
#pragma unroll
            for (int i = 0; i < 8; i++)
#pragma unroll
                for (int j = 0; j < 8; j++) acc[i][j] += ar[i] * br[j];
        }
        __syncthreads();
    }

    float4 bv0 = *(const float4*)(bias + bn + tx * 4);
    float4 bv1 = *(const float4*)(bias + bn + tx * 4 + 64);
    float bb[8] = {bv0.x, bv0.y, bv0.z, bv0.w, bv1.x, bv1.y, bv1.z, bv1.w};
#pragma unroll
    for (int i = 0; i < 8; i++) {
        int row = bm + ty * 4 + (i & 3) + (i >> 2) * 64;
        float4 v0, v1;
        v0.x = acc[i][0] + bb[0]; v0.y = acc[i][1] + bb[1];
        v0.z = acc[i][2] + bb[2]; v0.w = acc[i][3] + bb[3];
        v1.x = acc[i][4] + bb[4]; v1.y = acc[i][5] + bb[5];
        v1.z = acc[i][6] + bb[6]; v1.w = acc[i][7] + bb[7];
        if (relu) {
            v0.x = fmaxf(v0.x, 0.f); v0.y = fmaxf(v0.y, 0.f);
            v0.z = fmaxf(v0.z, 0.f); v0.w = fmaxf(v0.w, 0.f);
            v1.x = fmaxf(v1.x, 0.f); v1.y = fmaxf(v1.y, 0.f);
            v1.z = fmaxf(v1.z, 0.f); v1.w = fmaxf(v1.w, 0.f);
        }
        float* crow = C + (size_t)row * N + bn + tx * 4;
        *(float4*)crow = v0;
        *(float4*)(crow + 64) = v1;
    }
}

// ---------------------------------------------------------------------------
// Row-wise attention: one block per (b, h, q-row). S=512, dh=64.
// Q/K/V may live in fused buffers: row strides ldq / ldkv.
// causal=1: mask = max(tokens[b,k]==0, k>q); causal=0: mask = en_pad[b,k].
// ---------------------------------------------------------------------------
__global__ __launch_bounds__(256) void attn_kernel(
        const float* __restrict__ Q, const float* __restrict__ K,
        const float* __restrict__ Vv, const int* __restrict__ tokens,
        const float* __restrict__ en_pad, float* __restrict__ O,
        int ldq, int ldkv, int causal) {
    int qi = blockIdx.x;
    int h  = blockIdx.y;
    int b  = blockIdx.z;
    int t  = threadIdx.x;

    __shared__ __align__(16) float qs[DHEAD];
    __shared__ float sc[SEQ];
    __shared__ float red[256];
    __shared__ float ored[4][DHEAD];

    const float* qrow = Q + ((size_t)b * SEQ + qi) * ldq + h * DHEAD;
    if (t < DHEAD) qs[t] = qrow[t];
    __syncthreads();

    const float4* qs4 = (const float4*)qs;
    // scores (vectorized dot over dh=64)
    for (int j = t; j < SEQ; j += 256) {
        const float4* krow = (const float4*)(K + ((size_t)b * SEQ + j) * ldkv + h * DHEAD);
        float acc = 0.0f;
#pragma unroll
        for (int d = 0; d < DHEAD / 4; d++) {
            float4 kv = krow[d];
            float4 qv = qs4[d];
            acc += qv.x * kv.x + qv.y * kv.y + qv.z * kv.z + qv.w * kv.w;
        }
        float m;
        if (causal) {
            float pad = (tokens[b * SEQ + j] == 0) ? 1.0f : 0.0f;
            float tri = (j > qi) ? 1.0f : 0.0f;
            m = fmaxf(pad, tri);
        } else {
            m = en_pad[b * SEQ + j];
        }
        sc[j] = acc * 0.125f - m * 1.0e6f;
    }
    __syncthreads();

    // max
    float lm = -INFINITY;
    for (int j = t; j < SEQ; j += 256) lm = fmaxf(lm, sc[j]);
    red[t] = lm;
    __syncthreads();
    for (int off = 128; off > 0; off >>= 1) {
        if (t < off) red[t] = fmaxf(red[t], red[t + off]);
        __syncthreads();
    }
    float mx = red[0];
    __syncthreads();

    // exp + sum
    float ls = 0.0f;
    for (int j = t; j < SEQ; j += 256) {
        float e = expf(sc[j] - mx);
        sc[j] = e;
        ls += e;
    }
    red[t] = ls;
    __syncthreads();
    for (int off = 128; off > 0; off >>= 1) {
        if (t < off) red[t] += red[t + off];
        __syncthreads();
    }
    float ssum = red[0];
    __syncthreads();

    // output: thread t handles dim t&63, key-chunk t>>6 (4 chunks of 128)
    int d = t & 63;
    int chunk = t >> 6;
    float acc = 0.0f;
    const float* vbase = Vv + (size_t)b * SEQ * ldkv + h * DHEAD + d;
    for (int j = chunk * 128; j < (chunk + 1) * 128; j++)
        acc += sc[j] * vbase[(size_t)j * ldkv];
    ored[chunk][d] = acc;
    __syncthreads();
    if (t < DHEAD) {
        float o = (ored[0][t] + ored[1][t] + ored[2][t] + ored[3][t]) / ssum;
        O[((size_t)b * SEQ + qi) * DMODEL + h * DHEAD + t] = o;
    }
}

// ---------------------------------------------------------------------------
// out = LayerNorm(x + y) * g + b, row length 512, one block per row
// ---------------------------------------------------------------------------
__global__ __launch_bounds__(256) void ln_res_kernel(
        const float* __restrict__ x, const float* __restrict__ y,
        const float* __restrict__ g, const float* __restrict__ b,
        float* __restrict__ out) {
    int row = blockIdx.x;
    int t   = threadIdx.x;
    __shared__ float red[256];
    size_t base = (size_t)row * DMODEL;
    float v0 = x[base + t] + y[base + t];
    float v1 = x[base + t + 256] + y[base + t + 256];

    red[t] = v0 + v1;
    __syncthreads();
    for (int off = 128; off > 0; off >>= 1) {
        if (t < off) red[t] += red[t + off];
        __syncthreads();
    }
    float mu = red[0] * (1.0f / 512.0f);
    __syncthreads();

    float d0 = v0 - mu, d1 = v1 - mu;
    red[t] = d0 * d0 + d1 * d1;
    __syncthreads();
    for (int off = 128; off > 0; off >>= 1) {
        if (t < off) red[t] += red[t + off];
        __syncthreads();
    }
    float inv = rsqrtf(red[0] * (1.0f / 512.0f) + 1e-6f);
    out[base + t]       = d0 * inv * g[t]       + b[t];
    out[base + t + 256] = d1 * inv * g[t + 256] + b[t + 256];
}

// ---------------------------------------------------------------------------
extern "C" void kernel_launch(void* const* d_in, const int* in_sizes, int n_in,
                              void* d_out, int out_size, void* d_ws, size_t ws_size,
                              hipStream_t stream) {
    const int*   tokens = (const int*)  d_in[0];
    const float* en_out = (const float*)d_in[1];
    const float* en_pad = (const float*)d_in[2];
    const float* emb    = (const float*)d_in[3];
    const float* sa_w   = (const float*)d_in[4];
    const float* sa_b   = (const float*)d_in[5];
    const float* ca_w   = (const float*)d_in[6];
    const float* ca_b   = (const float*)d_in[7];
    const float* ff_w1  = (const float*)d_in[8];
    const float* ff_b1  = (const float*)d_in[9];
    const float* ff_w2  = (const float*)d_in[10];
    const float* ff_b2  = (const float*)d_in[11];
    const float* ln_g   = (const float*)d_in[12];
    const float* ln_b   = (const float*)d_in[13];
    const float* out_w  = (const float*)d_in[14];
    const float* out_b  = (const float*)d_in[15];
    float* logits = (float*)d_out;

    const int BS = BATCH * SEQ;               // 2048
    const size_t NTOK = (size_t)BS * DMODEL;  // 1 << 20

    // workspace layout (floats): 11*NTOK = 44 MB (same footprint as before)
    float* ws   = (float*)d_ws;
    float* buf0 = ws;                 // state A
    float* buf1 = ws + NTOK;          // state B
    float* qkv  = ws + 2 * NTOK;      // fused QKV [BS][1536] (3*NTOK)
    float* kv   = qkv + NTOK;         // cross K/V view [BS][1024] (aliases qkv+NTOK)
    float* att  = ws + 5 * NTOK;
    float* proj = ws + 6 * NTOK;
    float* ffb  = ws + 7 * NTOK;      // B*S*FF = 4M floats

    dim3 g_qkv(3 * DMODEL / 64, BS / 64);     // N=1536 fused q,k,v
    dim3 g_dd(DMODEL / 64, BS / 64);          // N=512
    dim3 g_kv(2 * DMODEL / 64, BS / 64);      // N=1024 fused k,v
    dim3 g_ff1(FFDIM / 128, BS / 128);        // 128x128 tiles, 256 blocks
    dim3 g_vocab(VOCAB / 128, BS / 128);      // 250 x 16
    dim3 attn_grid(SEQ, NHEAD, BATCH);

    embed_kernel<<<BS, 256, 0, stream>>>(tokens, emb, buf0);

    float* cur = buf0;
    float* oth = buf1;
    for (int l = 0; l < NLAYER; l++) {
        const float* sw = sa_w + (size_t)l * 4 * DMODEL * DMODEL;
        const float* sb = sa_b + (size_t)l * 4 * DMODEL;
        const float* cw = ca_w + (size_t)l * 4 * DMODEL * DMODEL;
        const float* cb = ca_b + (size_t)l * 4 * DMODEL;
        const float* lg = ln_g + (size_t)l * 3 * DMODEL;
        const float* lb = ln_b + (size_t)l * 3 * DMODEL;

        // ---- self-attention (q,k,v weights contiguous -> one N=1536 GEMM) ----
        gemm_bias_64<<<g_qkv, 256, 0, stream>>>(cur, sw, sb, qkv, BS, 3 * DMODEL, DMODEL, 0);
        attn_kernel<<<attn_grid, 256, 0, stream>>>(qkv, qkv + DMODEL, qkv + 2 * DMODEL,
                                                   tokens, nullptr, att,
                                                   3 * DMODEL, 3 * DMODEL, 1);
        gemm_bias_64<<<g_dd, 256, 0, stream>>>(att, sw + 3 * DMODEL * DMODEL, sb + 3 * DMODEL,
                                               proj, BS, DMODEL, DMODEL, 0);
        ln_res_kernel<<<BS, 256, 0, stream>>>(cur, proj, lg, lb, oth);   // h -> oth

        // ---- cross-attention (k,v weights contiguous -> one N=1024 GEMM) ----
        gemm_bias_64<<<g_dd, 256, 0, stream>>>(oth, cw, cb, qkv, BS, DMODEL, DMODEL, 0);
        gemm_bias_64<<<g_kv, 256, 0, stream>>>(en_out, cw + DMODEL * DMODEL, cb + DMODEL,
                                               kv, BS, 2 * DMODEL, DMODEL, 0);
        attn_kernel<<<attn_grid, 256, 0, stream>>>(qkv, kv, kv + DMODEL,
                                                   tokens, en_pad, att,
                                                   DMODEL, 2 * DMODEL, 0);
        gemm_bias_64<<<g_dd, 256, 0, stream>>>(att, cw + 3 * DMODEL * DMODEL, cb + 3 * DMODEL,
                                               proj, BS, DMODEL, DMODEL, 0);
        ln_res_kernel<<<BS, 256, 0, stream>>>(oth, proj, lg + DMODEL, lb + DMODEL, cur); // a -> cur

        // ---- feed-forward ----
        gemm_bias_128<<<g_ff1, 256, 0, stream>>>(cur, ff_w1 + (size_t)l * FFDIM * DMODEL,
                                                 ff_b1 + (size_t)l * FFDIM, ffb,
                                                 BS, FFDIM, DMODEL, 1);
        gemm_bias_64<<<g_dd, 256, 0, stream>>>(ffb, ff_w2 + (size_t)l * DMODEL * FFDIM,
                                               ff_b2 + (size_t)l * DMODEL, proj,
                                               BS, DMODEL, FFDIM, 0);
        ln_res_kernel<<<BS, 256, 0, stream>>>(cur, proj, lg + 2 * DMODEL, lb + 2 * DMODEL, oth);

        float* t2 = cur; cur = oth; oth = t2;
    }

    // final vocab projection (the big one: [2048,512]x[512,32000])
    gemm_bias_128<<<g_vocab, 256, 0, stream>>>(cur, out_w, out_b, logits, BS, VOCAB, DMODEL, 0);
}

// Round 2
// 4028.799 us; speedup vs baseline: 2.2755x; 2.0135x over previous
//
#include <hip/hip_runtime.h>
#include <math.h>

#define DMODEL 512
#define NHEAD  8
#define DHEAD  64
#define SEQ    512
#define BATCH  4
#define NLAYER 6
#define FFDIM  2048
#define VOCAB  32000

// ---------------------------------------------------------------------------
// Embedding * sqrt(D) + sinusoidal positional encoding
// ---------------------------------------------------------------------------
__global__ void embed_kernel(const int* __restrict__ tokens,
                             const float* __restrict__ emb,
                             float* __restrict__ x) {
    int idx = blockIdx.x;              // b*S + s
    int s   = idx & (SEQ - 1);
    int tok = tokens[idx];
    const float scale = 22.627416997969522f;  // sqrt(512)
    for (int d = threadIdx.x; d < DMODEL; d += blockDim.x) {
        float i2  = (float)((d >> 1) << 1) / (float)DMODEL;
        float inv = powf(10000.0f, -i2);
        float em  = (float)s * inv;
        float pe  = ((d & 1) == 0) ? sinf(em) : cosf(em);
        x[(size_t)idx * DMODEL + d] = emb[(size_t)tok * DMODEL + d] * scale + pe;
    }
}

// ---------------------------------------------------------------------------
// GEMM  C[m,n] = sum_k A[m,k]*W[n,k] + bias[n]  (optional ReLU)
// A:[M,K] row-major, W:[N,K] row-major (torch [out,in]).
// LDS transposed [k][row] so fragments are ds_read_b128.
// Grid: blockIdx.x = M-tiles (fastest) so co-resident blocks share W-tile.
// TK=32: barrier every 32 k-steps.
// ---------------------------------------------------------------------------
__global__ __launch_bounds__(256) void gemm_bias_64(
        const float* __restrict__ A, const float* __restrict__ W,
        const float* __restrict__ bias, float* __restrict__ C,
        int M, int N, int K, int relu) {
    __shared__ float As[32][68];
    __shared__ float Bs[32][68];
    int bm  = blockIdx.x * 64;
    int bn  = blockIdx.y * 64;
    int tid = threadIdx.x;
    int tx  = tid & 15;
    int ty  = tid >> 4;
    int lrow = tid >> 2;               // 0..63
    int lq   = (tid & 3) << 2;         // 0,4,8,12

    const float* Ap = A + (size_t)(bm + lrow) * K + lq;
    const float* Wp = W + (size_t)(bn + lrow) * K + lq;

    float acc[4][4] = {};
    float4 av0 = *(const float4*)Ap;
    float4 av1 = *(const float4*)(Ap + 16);
    float4 wv0 = *(const float4*)Wp;
    float4 wv1 = *(const float4*)(Wp + 16);

    for (int k0 = 0; k0 < K; k0 += 32) {
        As[lq + 0][lrow]  = av0.x; As[lq + 1][lrow]  = av0.y;
        As[lq + 2][lrow]  = av0.z; As[lq + 3][lrow]  = av0.w;
        As[lq + 16][lrow] = av1.x; As[lq + 17][lrow] = av1.y;
        As[lq + 18][lrow] = av1.z; As[lq + 19][lrow] = av1.w;
        Bs[lq + 0][lrow]  = wv0.x; Bs[lq + 1][lrow]  = wv0.y;
        Bs[lq + 2][lrow]  = wv0.z; Bs[lq + 3][lrow]  = wv0.w;
        Bs[lq + 16][lrow] = wv1.x; Bs[lq + 17][lrow] = wv1.y;
        Bs[lq + 18][lrow] = wv1.z; Bs[lq + 19][lrow] = wv1.w;
        __syncthreads();
        int kn = (k0 + 32 < K) ? k0 + 32 : k0;   // redundant last load, in-bounds
        av0 = *(const float4*)(Ap + kn);
        av1 = *(const float4*)(Ap + kn + 16);
        wv0 = *(const float4*)(Wp + kn);
        wv1 = *(const float4*)(Wp + kn + 16);
#pragma unroll
        for (int kk = 0; kk < 32; kk++) {
            float4 a = *(const float4*)&As[kk][ty * 4];
            float4 b = *(const float4*)&Bs[kk][tx * 4];
            float ar[4] = {a.x, a.y, a.z, a.w};
            float br[4] = {b.x, b.y, b.z, b.w};
#pragma unroll
            for (int i = 0; i < 4; i++)
#pragma unroll
                for (int j = 0; j < 4; j++) acc[i][j] += ar[i] * br[j];
        }
        __syncthreads();
    }

    float4 bv = *(const float4*)(bias + bn + tx * 4);
    float bb[4] = {bv.x, bv.y, bv.z, bv.w};
#pragma unroll
    for (int i = 0; i < 4; i++) {
        int row = bm + ty * 4 + i;
        float4 v;
        v.x = acc[i][0] + bb[0]; v.y = acc[i][1] + bb[1];
        v.z = acc[i][2] + bb[2]; v.w = acc[i][3] + bb[3];
        if (relu) {
            v.x = fmaxf(v.x, 0.f); v.y = fmaxf(v.y, 0.f);
            v.z = fmaxf(v.z, 0.f); v.w = fmaxf(v.w, 0.f);
        }
        *(float4*)(C + (size_t)row * N + bn + tx * 4) = v;
    }
}

__global__ __launch_bounds__(256) void gemm_bias_128(
        const float* __restrict__ A, const float* __restrict__ W,
        const float* __restrict__ bias, float* __restrict__ C,
        int M, int N, int K, int relu) {
    __shared__ float As[32][132];
    __shared__ float Bs[32][132];
    int bm  = blockIdx.x * 128;
    int bn  = blockIdx.y * 128;
    int tid = threadIdx.x;
    int tx  = tid & 15;
    int ty  = tid >> 4;
    int lrow = tid >> 2;
    int lq   = (tid & 3) << 2;

    const float* Ap  = A + (size_t)(bm + lrow) * K + lq;
    const float* Ap2 = Ap + (size_t)64 * K;
    const float* Wp  = W + (size_t)(bn + lrow) * K + lq;
    const float* Wp2 = Wp + (size_t)64 * K;

    float acc[8][8] = {};
    float4 a00 = *(const float4*)Ap;
    float4 a01 = *(const float4*)(Ap + 16);
    float4 a10 = *(const float4*)Ap2;
    float4 a11 = *(const float4*)(Ap2 + 16);
    float4 w00 = *(const float4*)Wp;
    float4 w01 = *(const float4*)(Wp + 16);
    float4 w10 = *(const float4*)Wp2;
    float4 w11 = *(const float4*)(Wp2 + 16);

    for (int k0 = 0; k0 < K; k0 += 32) {
        As[lq + 0][lrow]       = a00.x; As[lq + 1][lrow]       = a00.y;
        As[lq + 2][lrow]       = a00.z; As[lq + 3][lrow]       = a00.w;
        As[lq + 16][lrow]      = a01.x; As[lq + 17][lrow]      = a01.y;
        As[lq + 18][lrow]      = a01.z; As[lq + 19][lrow]      = a01.w;
        As[lq + 0][lrow + 64]  = a10.x; As[lq + 1][lrow + 64]  = a10.y;
        As[lq + 2][lrow + 64]  = a10.z; As[lq + 3][lrow + 64]  = a10.w;
        As[lq + 16][lrow + 64] = a11.x; As[lq + 17][lrow + 64] = a11.y;
        As[lq + 18][lrow + 64] = a11.z; As[lq + 19][lrow + 64] = a11.w;
        Bs[lq + 0][lrow]       = w00.x; Bs[lq + 1][lrow]       = w00.y;
        Bs[lq + 2][lrow]       = w00.z; Bs[lq + 3][lrow]       = w00.w;
        Bs[lq + 16][lrow]      = w01.x; Bs[lq + 17][lrow]      = w01.y;
        Bs[lq + 18][lrow]      = w01.z; Bs[lq + 19][lrow]      = w01.w;
        Bs[lq + 0][lrow + 64]  = w10.x; Bs[lq + 1][lrow + 64]  = w10.y;
        Bs[lq + 2][lrow + 64]  = w10.z; Bs[lq + 3][lrow + 64]  = w10.w;
        Bs[lq + 16][lrow + 64] = w11.x; Bs[lq + 17][lrow + 64] = w11.y;
        Bs[lq + 18][lrow + 64] = w11.z; Bs[lq + 19][lrow + 64] = w11.w;
        __syncthreads();
        int kn = (k0 + 32 < K) ? k0 + 32 : k0;
        a00 = *(const float4*)(Ap + kn);
        a01 = *(const float4*)(Ap + kn + 16);
        a10 = *(const float4*)(Ap2 + kn);
        a11 = *(const float4*)(Ap2 + kn + 16);
        w00 = *(const float4*)(Wp + kn);
        w01 = *(const float4*)(Wp + kn + 16);
        w10 = *(const float4*)(Wp2 + kn);
        w11 = *(const float4*)(Wp2 + kn + 16);
#pragma unroll
        for (int kk = 0; kk < 32; kk++) {
            float4 A0 = *(const float4*)&As[kk][ty * 4];
            float4 A1 = *(const float4*)&As[kk][ty * 4 + 64];
            float4 B0 = *(const float4*)&Bs[kk][tx * 4];
            float4 B1 = *(const float4*)&Bs[kk][tx * 4 + 64];
            float ar[8] = {A0.x, A0.y, A0.z, A0.w, A1.x, A1.y, A1.z, A1.w};
            float br[8] = {B0.x, B0.y, B0.z, B0.w, B1.x, B1.y, B1.z, B1.w};
#pragma unroll
            for (int i = 0; i < 8; i++)
#pragma unroll
                for (int j = 0; j < 8; j++) acc[i][j] += ar[i] * br[j];
        }
        __syncthreads();
    }

    float4 bv0 = *(const float4*)(bias + bn + tx * 4);
    float4 bv1 = *(const float4*)(bias + bn + tx * 4 + 64);
    float bb[8] = {bv0.x, bv0.y, bv0.z, bv0.w, bv1.x, bv1.y, bv1.z, bv1.w};
#pragma unroll
    for (int i = 0; i < 8; i++) {
        int row = bm + ty * 4 + (i & 3) + (i >> 2) * 64;
        float4 v0, v1;
        v0.x = acc[i][0] + bb[0]; v0.y = acc[i][1] + bb[1];
        v0.z = acc[i][2] + bb[2]; v0.w = acc[i][3] + bb[3];
        v1.x = acc[i][4] + bb[4]; v1.y = acc[i][5] + bb[5];
        v1.z = acc[i][6] + bb[6]; v1.w = acc[i][7] + bb[7];
        if (relu) {
            v0.x = fmaxf(v0.x, 0.f); v0.y = fmaxf(v0.y, 0.f);
            v0.z = fmaxf(v0.z, 0.f); v0.w = fmaxf(v0.w, 0.f);
            v1.x = fmaxf(v1.x, 0.f); v1.y = fmaxf(v1.y, 0.f);
            v1.z = fmaxf(v1.z, 0.f); v1.w = fmaxf(v1.w, 0.f);
        }
        float* crow = C + (size_t)row * N + bn + tx * 4;
        *(float4*)crow = v0;
        *(float4*)(crow + 64) = v1;
    }
}

// ---------------------------------------------------------------------------
// Tiled flash attention: block = (qtile of 64 rows, h, b), 256 threads.
// QK^T and PV are register GEMMs (4x4 micro) fed from LDS; online softmax
// via width-16 shuffles. P aliases the K buffer (53KB LDS total).
// causal=1: mask = max(tokens[b,k]==0, k>q), chunks ct>qt skipped.
// causal=0: mask = en_pad[b,k].
// ---------------------------------------------------------------------------
__global__ __launch_bounds__(256) void attn_tile_kernel(
        const float* __restrict__ Q, const float* __restrict__ K,
        const float* __restrict__ Vv, const int* __restrict__ tokens,
        const float* __restrict__ en_pad, float* __restrict__ O,
        int ldq, int ldkv, int causal) {
    int qt  = blockIdx.x;              // 0..7
    int h   = blockIdx.y;
    int b   = blockIdx.z;
    int tid = threadIdx.x;
    int tx  = tid & 15;
    int ty  = tid >> 4;
    int lrow = tid >> 2;               // 0..63
    int lq4  = tid & 3;

    __shared__ float Qs[DHEAD][68];    // [d][qrow]  (transposed)
    __shared__ float KP[64][68];       // K as [d][j], then P as [qrow][j]
    __shared__ float Vs[64][72];       // [j][d]  (natural)

    // stage Q tile transposed (once)
    {
        const float* qbase = Q + ((size_t)b * SEQ + qt * 64 + lrow) * ldq + h * DHEAD;
#pragma unroll
        for (int i = 0; i < 4; i++) {
            int dk = (lq4 + i * 4) * 4;
            float4 f = *(const float4*)(qbase + dk);
            Qs[dk + 0][lrow] = f.x; Qs[dk + 1][lrow] = f.y;
            Qs[dk + 2][lrow] = f.z; Qs[dk + 3][lrow] = f.w;
        }
    }

    float o[4][4] = {};
    float mrow[4] = {-INFINITY, -INFINITY, -INFINITY, -INFINITY};
    float lsum[4] = {0.f, 0.f, 0.f, 0.f};
    int nc = causal ? (qt + 1) : (SEQ / 64);

    for (int ct = 0; ct < nc; ct++) {
        __syncthreads();               // protect KP/Vs from previous readers
        const float* kbase = K  + ((size_t)b * SEQ + ct * 64 + lrow) * ldkv + h * DHEAD;
        const float* vbase = Vv + ((size_t)b * SEQ + ct * 64 + lrow) * ldkv + h * DHEAD;
#pragma unroll
        for (int i = 0; i < 4; i++) {
            int dk = (lq4 + i * 4) * 4;
            float4 f = *(const float4*)(kbase + dk);
            KP[dk + 0][lrow] = f.x; KP[dk + 1][lrow] = f.y;
            KP[dk + 2][lrow] = f.z; KP[dk + 3][lrow] = f.w;
            float4 g = *(const float4*)(vbase + dk);
            *(float4*)&Vs[lrow][dk] = g;
        }
        __syncthreads();

        // S = Q K^T  (4x4 frag)
        float s[4][4] = {};
#pragma unroll
        for (int d = 0; d < DHEAD; d++) {
            float4 a  = *(const float4*)&Qs[d][ty * 4];
            float4 bb = *(const float4*)&KP[d][tx * 4];
            float ar[4] = {a.x, a.y, a.z, a.w};
            float br[4] = {bb.x, bb.y, bb.z, bb.w};
#pragma unroll
            for (int i = 0; i < 4; i++)
#pragma unroll
                for (int j = 0; j < 4; j++) s[i][j] += ar[i] * br[j];
        }
        __syncthreads();               // done reading KP as K

        // mask + scale
        float cmask[4];
#pragma unroll
        for (int j = 0; j < 4; j++) {
            int jg = ct * 64 + tx * 4 + j;
            cmask[j] = causal ? ((tokens[b * SEQ + jg] == 0) ? 1.0f : 0.0f)
                              : en_pad[b * SEQ + jg];
        }
#pragma unroll
        for (int i = 0; i < 4; i++) {
            int qg = qt * 64 + ty * 4 + i;
#pragma unroll
            for (int j = 0; j < 4; j++) {
                int jg = ct * 64 + tx * 4 + j;
                float mk = cmask[j];
                if (causal && jg > qg) mk = 1.0f;
                s[i][j] = s[i][j] * 0.125f - mk * 1.0e6f;
            }
        }

        // online softmax update (row stats across the 16 tx lanes)
#pragma unroll
        for (int i = 0; i < 4; i++) {
            float rm = fmaxf(fmaxf(s[i][0], s[i][1]), fmaxf(s[i][2], s[i][3]));
#pragma unroll
            for (int msk = 1; msk < 16; msk <<= 1)
                rm = fmaxf(rm, __shfl_xor(rm, msk));
            float mn = fmaxf(mrow[i], rm);
            float sc = expf(mrow[i] - mn);     // 0 on first chunk (m=-inf)
            mrow[i] = mn;
            float ps = 0.0f;
#pragma unroll
            for (int j = 0; j < 4; j++) {
                float p = expf(s[i][j] - mn);
                s[i][j] = p;
                ps += p;
            }
#pragma unroll
            for (int msk = 1; msk < 16; msk <<= 1)
                ps += __shfl_xor(ps, msk);
            lsum[i] = lsum[i] * sc + ps;
#pragma unroll
            for (int j = 0; j < 4; j++) o[i][j] *= sc;
        }

        // write P row-major into KP
#pragma unroll
        for (int i = 0; i < 4; i++)
            *(float4*)&KP[ty * 4 + i][tx * 4] =
                make_float4(s[i][0], s[i][1], s[i][2], s[i][3]);
        __syncthreads();

        // O += P V  (k-unrolled by 4, all b128 reads)
#pragma unroll
        for (int k0 = 0; k0 < 64; k0 += 4) {
            float4 a0 = *(const float4*)&KP[ty * 4 + 0][k0];
            float4 a1 = *(const float4*)&KP[ty * 4 + 1][k0];
            float4 a2 = *(const float4*)&KP[ty * 4 + 2][k0];
            float4 a3 = *(const float4*)&KP[ty * 4 + 3][k0];
            float ar[4][4] = {{a0.x, a0.y, a0.z, a0.w},
                              {a1.x, a1.y, a1.z, a1.w},
                              {a2.x, a2.y, a2.z, a2.w},
                              {a3.x, a3.y, a3.z, a3.w}};
#pragma unroll
            for (int kk = 0; kk < 4; kk++) {
                float4 bv = *(const float4*)&Vs[k0 + kk][tx * 4];
                float br[4] = {bv.x, bv.y, bv.z, bv.w};
#pragma unroll
                for (int i = 0; i < 4; i++)
#pragma unroll
                    for (int j = 0; j < 4; j++) o[i][j] += ar[i][kk] * br[j];
            }
        }
    }

    // epilogue: normalize and write
#pragma unroll
    for (int i = 0; i < 4; i++) {
        float inv = 1.0f / lsum[i];
        float4 v = make_float4(o[i][0] * inv, o[i][1] * inv,
                               o[i][2] * inv, o[i][3] * inv);
        *(float4*)(O + ((size_t)b * SEQ + qt * 64 + ty * 4 + i) * DMODEL
                   + h * DHEAD + tx * 4) = v;
    }
}

// ---------------------------------------------------------------------------
// out = LayerNorm(x + y) * g + b, row length 512, one WAVE per row (no barriers)
// ---------------------------------------------------------------------------
__global__ __launch_bounds__(64) void ln_res_kernel(
        const float* __restrict__ x, const float* __restrict__ y,
        const float* __restrict__ g, const float* __restrict__ b,
        float* __restrict__ out) {
    int row = blockIdx.x;
    int t   = threadIdx.x;             // 0..63
    size_t base = (size_t)row * DMODEL;
    const float4* x4 = (const float4*)(x + base);
    const float4* y4 = (const float4*)(y + base);
    float4 a0 = x4[t], a1 = x4[t + 64];
    float4 c0 = y4[t], c1 = y4[t + 64];
    float v0x = a0.x + c0.x, v0y = a0.y + c0.y, v0z = a0.z + c0.z, v0w = a0.w + c0.w;
    float v1x = a1.x + c1.x, v1y = a1.y + c1.y, v1z = a1.z + c1.z, v1w = a1.w + c1.w;

    float s = v0x + v0y + v0z + v0w + v1x + v1y + v1z + v1w;
#pragma unroll
    for (int m = 1; m < 64; m <<= 1) s += __shfl_xor(s, m);
    float mu = s * (1.0f / 512.0f);

    float d0x = v0x - mu, d0y = v0y - mu, d0z = v0z - mu, d0w = v0w - mu;
    float d1x = v1x - mu, d1y = v1y - mu, d1z = v1z - mu, d1w = v1w - mu;
    float q = d0x * d0x + d0y * d0y + d0z * d0z + d0w * d0w
            + d1x * d1x + d1y * d1y + d1z * d1z + d1w * d1w;
#pragma unroll
    for (int m = 1; m < 64; m <<= 1) q += __shfl_xor(q, m);
    float inv = rsqrtf(q * (1.0f / 512.0f) + 1e-6f);

    const float4* g4 = (const float4*)g;
    const float4* b4 = (const float4*)b;
    float4 gv0 = g4[t], gv1 = g4[t + 64];
    float4 bv0 = b4[t], bv1 = b4[t + 64];
    float4* o4 = (float4*)(out + base);
    o4[t]      = make_float4(d0x * inv * gv0.x + bv0.x, d0y * inv * gv0.y + bv0.y,
                             d0z * inv * gv0.z + bv0.z, d0w * inv * gv0.w + bv0.w);
    o4[t + 64] = make_float4(d1x * inv * gv1.x + bv1.x, d1y * inv * gv1.y + bv1.y,
                             d1z * inv * gv1.z + bv1.z, d1w * inv * gv1.w + bv1.w);
}

// ---------------------------------------------------------------------------
extern "C" void kernel_launch(void* const* d_in, const int* in_sizes, int n_in,
                              void* d_out, int out_size, void* d_ws, size_t ws_size,
                              hipStream_t stream) {
    const int*   tokens = (const int*)  d_in[0];
    const float* en_out = (const float*)d_in[1];
    const float* en_pad = (const float*)d_in[2];
    const float* emb    = (const float*)d_in[3];
    const float* sa_w   = (const float*)d_in[4];
    const float* sa_b   = (const float*)d_in[5];
    const float* ca_w   = (const float*)d_in[6];
    const float* ca_b   = (const float*)d_in[7];
    const float* ff_w1  = (const float*)d_in[8];
    const float* ff_b1  = (const float*)d_in[9];
    const float* ff_w2  = (const float*)d_in[10];
    const float* ff_b2  = (const float*)d_in[11];
    const float* ln_g   = (const float*)d_in[12];
    const float* ln_b   = (const float*)d_in[13];
    const float* out_w  = (const float*)d_in[14];
    const float* out_b  = (const float*)d_in[15];
    float* logits = (float*)d_out;

    const int BS = BATCH * SEQ;               // 2048
    const size_t NTOK = (size_t)BS * DMODEL;  // 1 << 20

    float* ws   = (float*)d_ws;
    float* buf0 = ws;                 // state A
    float* buf1 = ws + NTOK;          // state B
    float* qkv  = ws + 2 * NTOK;      // fused QKV [BS][1536]
    float* kv   = qkv + NTOK;         // cross K/V view [BS][1024]
    float* att  = ws + 5 * NTOK;
    float* proj = ws + 6 * NTOK;
    float* ffb  = ws + 7 * NTOK;      // B*S*FF

    // grids: x = M-tiles (fastest -> W-tile reuse), y = N-tiles
    dim3 g_qkv(BS / 64, 3 * DMODEL / 64);
    dim3 g_dd(BS / 64, DMODEL / 64);
    dim3 g_kv(BS / 64, 2 * DMODEL / 64);
    dim3 g_ff1(BS / 128, FFDIM / 128);
    dim3 g_vocab(BS / 128, VOCAB / 128);
    dim3 attn_grid(SEQ / 64, NHEAD, BATCH);

    embed_kernel<<<BS, 256, 0, stream>>>(tokens, emb, buf0);

    float* cur = buf0;
    float* oth = buf1;
    for (int l = 0; l < NLAYER; l++) {
        const float* sw = sa_w + (size_t)l * 4 * DMODEL * DMODEL;
        const float* sb = sa_b + (size_t)l * 4 * DMODEL;
        const float* cw = ca_w + (size_t)l * 4 * DMODEL * DMODEL;
        const float* cb = ca_b + (size_t)l * 4 * DMODEL;
        const float* lg = ln_g + (size_t)l * 3 * DMODEL;
        const float* lb = ln_b + (size_t)l * 3 * DMODEL;

        // ---- self-attention ----
        gemm_bias_64<<<g_qkv, 256, 0, stream>>>(cur, sw, sb, qkv, BS, 3 * DMODEL, DMODEL, 0);
        attn_tile_kernel<<<attn_grid, 256, 0, stream>>>(qkv, qkv + DMODEL, qkv + 2 * DMODEL,
                                                        tokens, nullptr, att,
                                                        3 * DMODEL, 3 * DMODEL, 1);
        gemm_bias_64<<<g_dd, 256, 0, stream>>>(att, sw + 3 * DMODEL * DMODEL, sb + 3 * DMODEL,
                                               proj, BS, DMODEL, DMODEL, 0);
        ln_res_kernel<<<BS, 64, 0, stream>>>(cur, proj, lg, lb, oth);

        // ---- cross-attention ----
        gemm_bias_64<<<g_dd, 256, 0, stream>>>(oth, cw, cb, qkv, BS, DMODEL, DMODEL, 0);
        gemm_bias_64<<<g_kv, 256, 0, stream>>>(en_out, cw + DMODEL * DMODEL, cb + DMODEL,
                                               kv, BS, 2 * DMODEL, DMODEL, 0);
        attn_tile_kernel<<<attn_grid, 256, 0, stream>>>(qkv, kv, kv + DMODEL,
                                                        tokens, en_pad, att,
                                                        DMODEL, 2 * DMODEL, 0);
        gemm_bias_64<<<g_dd, 256, 0, stream>>>(att, cw + 3 * DMODEL * DMODEL, cb + 3 * DMODEL,
                                               proj, BS, DMODEL, DMODEL, 0);
        ln_res_kernel<<<BS, 64, 0, stream>>>(oth, proj, lg + DMODEL, lb + DMODEL, cur);

        // ---- feed-forward ----
        gemm_bias_128<<<g_ff1, 256, 0, stream>>>(cur, ff_w1 + (size_t)l * FFDIM * DMODEL,
                                                 ff_b1 + (size_t)l * FFDIM, ffb,
                                                 BS, FFDIM, DMODEL, 1);
        gemm_bias_64<<<g_dd, 256, 0, stream>>>(ffb, ff_w2 + (size_t)l * DMODEL * FFDIM,
                                               ff_b2 + (size_t)l * DMODEL, proj,
                                               BS, DMODEL, FFDIM, 0);
        ln_res_kernel<<<BS, 64, 0, stream>>>(cur, proj, lg + 2 * DMODEL, lb + 2 * DMODEL, oth);

        float* t2 = cur; cur = oth; oth = t2;
    }

    // final vocab projection
    gemm_bias_128<<<g_vocab, 256, 0, stream>>>(cur, out_w, out_b, logits, BS, VOCAB, DMODEL, 0);
}

// Round 3
// 3471.167 us; speedup vs baseline: 2.6410x; 1.1606x over previous
//
#include <hip/hip_runtime.h>
#include <math.h>

#define DMODEL 512
#define NHEAD  8
#define DHEAD  64
#define SEQ    512
#define BATCH  4
#define NLAYER 6
#define FFDIM  2048
#define VOCAB  32000

using bf16x8 = __attribute__((ext_vector_type(8))) __bf16;
using f32x4  = __attribute__((ext_vector_type(4))) float;
typedef unsigned int uint32;
typedef unsigned short ushort16;

// ---------------------------------------------------------------------------
// Embedding * sqrt(D) + sinusoidal positional encoding
// ---------------------------------------------------------------------------
__global__ void embed_kernel(const int* __restrict__ tokens,
                             const float* __restrict__ emb,
                             float* __restrict__ x) {
    int idx = blockIdx.x;              // b*S + s
    int s   = idx & (SEQ - 1);
    int tok = tokens[idx];
    const float scale = 22.627416997969522f;  // sqrt(512)
    for (int d = threadIdx.x; d < DMODEL; d += blockDim.x) {
        float i2  = (float)((d >> 1) << 1) / (float)DMODEL;
        float inv = powf(10000.0f, -i2);
        float em  = (float)s * inv;
        float pe  = ((d & 1) == 0) ? sinf(em) : cosf(em);
        x[(size_t)idx * DMODEL + d] = emb[(size_t)tok * DMODEL + d] * scale + pe;
    }
}

// ---------------------------------------------------------------------------
// fp32 -> bf16 triple split (truncation at each level; residual exact).
// x ~= s0 + s1 + s2 with |s1|<=2^-8|x|, |s2|<=2^-16|x|, dropped < 2^-24|x|.
// ---------------------------------------------------------------------------
__device__ __forceinline__ void split3(float x, ushort16& s0, ushort16& s1, ushort16& s2) {
    uint32 u0 = __builtin_bit_cast(uint32, x);
    s0 = (ushort16)(u0 >> 16);
    float r1 = x - __builtin_bit_cast(float, u0 & 0xffff0000u);
    uint32 u1 = __builtin_bit_cast(uint32, r1);
    s1 = (ushort16)(u1 >> 16);
    float r2 = r1 - __builtin_bit_cast(float, u1 & 0xffff0000u);
    s2 = (ushort16)(__builtin_bit_cast(uint32, r2) >> 16);
}

// ---------------------------------------------------------------------------
// MFMA GEMM with fp32 emulated by bf16x3 split (6 MFMA products, ~2^-24 rel).
// C[m,n] = sum_k A[m,k]*W[n,k] + bias[n]  (optional ReLU)
// 128x128 tile, 4 waves (each a 64x64 quadrant of 4x4 16x16x32-MFMA frags),
// K-step 32. LDS: 3 split-planes per matrix, rows padded to 40 ushorts
// (80B stride -> frag ds_read_b128 spreads over all 32 banks, ~2-way).
// Requires M%128==0, N%128==0, K%32==0.
// ---------------------------------------------------------------------------
#define LDSP 40
__global__ __launch_bounds__(256, 2) void gemm_mfma3(
        const float* __restrict__ A, const float* __restrict__ W,
        const float* __restrict__ bias, float* __restrict__ C,
        int M, int N, int K, int relu) {
    __shared__ ushort16 As[3][128][LDSP];
    __shared__ ushort16 Bs[3][128][LDSP];
    int bm  = blockIdx.x * 128;
    int bn  = blockIdx.y * 128;
    int tid = threadIdx.x;
    int w   = tid >> 6;
    int l   = tid & 63;
    int wrow = (w >> 1) * 64;
    int wcol = (w & 1) * 64;
    int r2  = tid >> 2;                 // 0..63 staging row (and +64)
    int qq  = tid & 3;                  // k-quad

    const float* Abase = A + (size_t)(bm + r2) * K + qq * 4;
    const float* Wbase = W + (size_t)(bn + r2) * K + qq * 4;
    const size_t rowK64 = (size_t)64 * K;

    f32x4 acc[4][4];
#pragma unroll
    for (int i = 0; i < 4; i++)
#pragma unroll
        for (int j = 0; j < 4; j++) acc[i][j] = (f32x4){0.f, 0.f, 0.f, 0.f};

    float4 va[4], vw[4];
    // prefetch k-slab 0:  combos c=(h,g): row +64h, k +16g
#pragma unroll
    for (int c = 0; c < 4; c++) {
        size_t off = (size_t)(c >> 1) * rowK64 + (c & 1) * 16;
        va[c] = *(const float4*)(Abase + off);
        vw[c] = *(const float4*)(Wbase + off);
    }

    for (int k0 = 0; k0 < K; k0 += 32) {
        // convert + store to LDS
#pragma unroll
        for (int c = 0; c < 4; c++) {
            int row = r2 + ((c >> 1) << 6);
            int kb  = (qq << 2) + ((c & 1) << 4);
            float xa[4] = {va[c].x, va[c].y, va[c].z, va[c].w};
            float xw[4] = {vw[c].x, vw[c].y, vw[c].z, vw[c].w};
            ushort16 a0[4], a1[4], a2[4], w0[4], w1[4], w2[4];
#pragma unroll
            for (int e = 0; e < 4; e++) {
                split3(xa[e], a0[e], a1[e], a2[e]);
                split3(xw[e], w0[e], w1[e], w2[e]);
            }
            *(uint32*)&As[0][row][kb]     = (uint32)a0[0] | ((uint32)a0[1] << 16);
            *(uint32*)&As[0][row][kb + 2] = (uint32)a0[2] | ((uint32)a0[3] << 16);
            *(uint32*)&As[1][row][kb]     = (uint32)a1[0] | ((uint32)a1[1] << 16);
            *(uint32*)&As[1][row][kb + 2] = (uint32)a1[2] | ((uint32)a1[3] << 16);
            *(uint32*)&As[2][row][kb]     = (uint32)a2[0] | ((uint32)a2[1] << 16);
            *(uint32*)&As[2][row][kb + 2] = (uint32)a2[2] | ((uint32)a2[3] << 16);
            *(uint32*)&Bs[0][row][kb]     = (uint32)w0[0] | ((uint32)w0[1] << 16);
            *(uint32*)&Bs[0][row][kb + 2] = (uint32)w0[2] | ((uint32)w0[3] << 16);
            *(uint32*)&Bs[1][row][kb]     = (uint32)w1[0] | ((uint32)w1[1] << 16);
            *(uint32*)&Bs[1][row][kb + 2] = (uint32)w1[2] | ((uint32)w1[3] << 16);
            *(uint32*)&Bs[2][row][kb]     = (uint32)w2[0] | ((uint32)w2[1] << 16);
            *(uint32*)&Bs[2][row][kb + 2] = (uint32)w2[2] | ((uint32)w2[3] << 16);
        }
        __syncthreads();

        // prefetch next k-slab (overlaps MFMA section)
        if (k0 + 32 < K) {
#pragma unroll
            for (int c = 0; c < 4; c++) {
                size_t off = (size_t)(c >> 1) * rowK64 + (c & 1) * 16 + k0 + 32;
                va[c] = *(const float4*)(Abase + off);
                vw[c] = *(const float4*)(Wbase + off);
            }
        }

        // fragment loads + 6-product MFMA accumulation
        int fr = l & 15;                 // frag row/col lane index
        int kg = (l >> 4) * 8;           // k-group offset (8 bf16)
        bf16x8 bf[3][4];
#pragma unroll
        for (int nj = 0; nj < 4; nj++) {
            int rowb = wcol + nj * 16 + fr;
            bf[0][nj] = *(const bf16x8*)&Bs[0][rowb][kg];
            bf[1][nj] = *(const bf16x8*)&Bs[1][rowb][kg];
            bf[2][nj] = *(const bf16x8*)&Bs[2][rowb][kg];
        }
#pragma unroll
        for (int mi = 0; mi < 4; mi++) {
            int rowa = wrow + mi * 16 + fr;
            bf16x8 af0 = *(const bf16x8*)&As[0][rowa][kg];
            bf16x8 af1 = *(const bf16x8*)&As[1][rowa][kg];
            bf16x8 af2 = *(const bf16x8*)&As[2][rowa][kg];
#pragma unroll
            for (int nj = 0; nj < 4; nj++) {
                f32x4 a = acc[mi][nj];
                a = __builtin_amdgcn_mfma_f32_16x16x32_bf16(af2, bf[0][nj], a, 0, 0, 0);
                a = __builtin_amdgcn_mfma_f32_16x16x32_bf16(af1, bf[1][nj], a, 0, 0, 0);
                a = __builtin_amdgcn_mfma_f32_16x16x32_bf16(af0, bf[2][nj], a, 0, 0, 0);
                a = __builtin_amdgcn_mfma_f32_16x16x32_bf16(af1, bf[0][nj], a, 0, 0, 0);
                a = __builtin_amdgcn_mfma_f32_16x16x32_bf16(af0, bf[1][nj], a, 0, 0, 0);
                a = __builtin_amdgcn_mfma_f32_16x16x32_bf16(af0, bf[0][nj], a, 0, 0, 0);
                acc[mi][nj] = a;
            }
        }
        __syncthreads();
    }

    // epilogue: C/D layout col = lane&15, row = (lane>>4)*4 + reg  [m89]
    int cl = l & 15;
    int rh = (l >> 4) * 4;
#pragma unroll
    for (int nj = 0; nj < 4; nj++) {
        int col = bn + wcol + nj * 16 + cl;
        float bv = bias[col];
#pragma unroll
        for (int mi = 0; mi < 4; mi++) {
            f32x4 a = acc[mi][nj];
            int rbase = bm + wrow + mi * 16 + rh;
#pragma unroll
            for (int r = 0; r < 4; r++) {
                float v = a[r] + bv;
                if (relu) v = fmaxf(v, 0.0f);
                C[(size_t)(rbase + r) * N + col] = v;
            }
        }
    }
}

// ---------------------------------------------------------------------------
// fp32 GEMM (kept for N=512 shapes / FF2): 64x64 tile, TK=32, 4x4 micro,
// LDS transposed [k][row] so fragments are ds_read_b128.
// ---------------------------------------------------------------------------
__global__ __launch_bounds__(256) void gemm_bias_64(
        const float* __restrict__ A, const float* __restrict__ W,
        const float* __restrict__ bias, float* __restrict__ C,
        int M, int N, int K, int relu) {
    __shared__ float As[32][68];
    __shared__ float Bs[32][68];
    int bm  = blockIdx.x * 64;
    int bn  = blockIdx.y * 64;
    int tid = threadIdx.x;
    int tx  = tid & 15;
    int ty  = tid >> 4;
    int lrow = tid >> 2;               // 0..63
    int lq   = (tid & 3) << 2;         // 0,4,8,12

    const float* Ap = A + (size_t)(bm + lrow) * K + lq;
    const float* Wp = W + (size_t)(bn + lrow) * K + lq;

    float acc[4][4] = {};
    float4 av0 = *(const float4*)Ap;
    float4 av1 = *(const float4*)(Ap + 16);
    float4 wv0 = *(const float4*)Wp;
    float4 wv1 = *(const float4*)(Wp + 16);

    for (int k0 = 0; k0 < K; k0 += 32) {
        As[lq + 0][lrow]  = av0.x; As[lq + 1][lrow]  = av0.y;
        As[lq + 2][lrow]  = av0.z; As[lq + 3][lrow]  = av0.w;
        As[lq + 16][lrow] = av1.x; As[lq + 17][lrow] = av1.y;
        As[lq + 18][lrow] = av1.z; As[lq + 19][lrow] = av1.w;
        Bs[lq + 0][lrow]  = wv0.x; Bs[lq + 1][lrow]  = wv0.y;
        Bs[lq + 2][lrow]  = wv0.z; Bs[lq + 3][lrow]  = wv0.w;
        Bs[lq + 16][lrow] = wv1.x; Bs[lq + 17][lrow] = wv1.y;
        Bs[lq + 18][lrow] = wv1.z; Bs[lq + 19][lrow] = wv1.w;
        __syncthreads();
        int kn = (k0 + 32 < K) ? k0 + 32 : k0;   // redundant last load, in-bounds
        av0 = *(const float4*)(Ap + kn);
        av1 = *(const float4*)(Ap + kn + 16);
        wv0 = *(const float4*)(Wp + kn);
        wv1 = *(const float4*)(Wp + kn + 16);
#pragma unroll
        for (int kk = 0; kk < 32; kk++) {
            float4 a = *(const float4*)&As[kk][ty * 4];
            float4 b = *(const float4*)&Bs[kk][tx * 4];
            float ar[4] = {a.x, a.y, a.z, a.w};
            float br[4] = {b.x, b.y, b.z, b.w};
#pragma unroll
            for (int i = 0; i < 4; i++)
#pragma unroll
                for (int j = 0; j < 4; j++) acc[i][j] += ar[i] * br[j];
        }
        __syncthreads();
    }

    float4 bv = *(const float4*)(bias + bn + tx * 4);
    float bb[4] = {bv.x, bv.y, bv.z, bv.w};
#pragma unroll
    for (int i = 0; i < 4; i++) {
        int row = bm + ty * 4 + i;
        float4 v;
        v.x = acc[i][0] + bb[0]; v.y = acc[i][1] + bb[1];
        v.z = acc[i][2] + bb[2]; v.w = acc[i][3] + bb[3];
        if (relu) {
            v.x = fmaxf(v.x, 0.f); v.y = fmaxf(v.y, 0.f);
            v.z = fmaxf(v.z, 0.f); v.w = fmaxf(v.w, 0.f);
        }
        *(float4*)(C + (size_t)row * N + bn + tx * 4) = v;
    }
}

// ---------------------------------------------------------------------------
// Tiled flash attention: block = (qtile of 64 rows, h, b), 256 threads.
// ---------------------------------------------------------------------------
__global__ __launch_bounds__(256) void attn_tile_kernel(
        const float* __restrict__ Q, const float* __restrict__ K,
        const float* __restrict__ Vv, const int* __restrict__ tokens,
        const float* __restrict__ en_pad, float* __restrict__ O,
        int ldq, int ldkv, int causal) {
    int qt  = blockIdx.x;              // 0..7
    int h   = blockIdx.y;
    int b   = blockIdx.z;
    int tid = threadIdx.x;
    int tx  = tid & 15;
    int ty  = tid >> 4;
    int lrow = tid >> 2;               // 0..63
    int lq4  = tid & 3;

    __shared__ float Qs[DHEAD][68];    // [d][qrow]  (transposed)
    __shared__ float KP[64][68];       // K as [d][j], then P as [qrow][j]
    __shared__ float Vs[64][72];       // [j][d]  (natural)

    {
        const float* qbase = Q + ((size_t)b * SEQ + qt * 64 + lrow) * ldq + h * DHEAD;
#pragma unroll
        for (int i = 0; i < 4; i++) {
            int dk = (lq4 + i * 4) * 4;
            float4 f = *(const float4*)(qbase + dk);
            Qs[dk + 0][lrow] = f.x; Qs[dk + 1][lrow] = f.y;
            Qs[dk + 2][lrow] = f.z; Qs[dk + 3][lrow] = f.w;
        }
    }

    float o[4][4] = {};
    float mrow[4] = {-INFINITY, -INFINITY, -INFINITY, -INFINITY};
    float lsum[4] = {0.f, 0.f, 0.f, 0.f};
    int nc = causal ? (qt + 1) : (SEQ / 64);

    for (int ct = 0; ct < nc; ct++) {
        __syncthreads();
        const float* kbase = K  + ((size_t)b * SEQ + ct * 64 + lrow) * ldkv + h * DHEAD;
        const float* vbase = Vv + ((size_t)b * SEQ + ct * 64 + lrow) * ldkv + h * DHEAD;
#pragma unroll
        for (int i = 0; i < 4; i++) {
            int dk = (lq4 + i * 4) * 4;
            float4 f = *(const float4*)(kbase + dk);
            KP[dk + 0][lrow] = f.x; KP[dk + 1][lrow] = f.y;
            KP[dk + 2][lrow] = f.z; KP[dk + 3][lrow] = f.w;
            float4 g = *(const float4*)(vbase + dk);
            *(float4*)&Vs[lrow][dk] = g;
        }
        __syncthreads();

        float s[4][4] = {};
#pragma unroll
        for (int d = 0; d < DHEAD; d++) {
            float4 a  = *(const float4*)&Qs[d][ty * 4];
            float4 bb = *(const float4*)&KP[d][tx * 4];
            float ar[4] = {a.x, a.y, a.z, a.w};
            float br[4] = {bb.x, bb.y, bb.z, bb.w};
#pragma unroll
            for (int i = 0; i < 4; i++)
#pragma unroll
                for (int j = 0; j < 4; j++) s[i][j] += ar[i] * br[j];
        }
        __syncthreads();

        float cmask[4];
#pragma unroll
        for (int j = 0; j < 4; j++) {
            int jg = ct * 64 + tx * 4 + j;
            cmask[j] = causal ? ((tokens[b * SEQ + jg] == 0) ? 1.0f : 0.0f)
                              : en_pad[b * SEQ + jg];
        }
#pragma unroll
        for (int i = 0; i < 4; i++) {
            int qg = qt * 64 + ty * 4 + i;
#pragma unroll
            for (int j = 0; j < 4; j++) {
                int jg = ct * 64 + tx * 4 + j;
                float mk = cmask[j];
                if (causal && jg > qg) mk = 1.0f;
                s[i][j] = s[i][j] * 0.125f - mk * 1.0e6f;
            }
        }

#pragma unroll
        for (int i = 0; i < 4; i++) {
            float rm = fmaxf(fmaxf(s[i][0], s[i][1]), fmaxf(s[i][2], s[i][3]));
#pragma unroll
            for (int msk = 1; msk < 16; msk <<= 1)
                rm = fmaxf(rm, __shfl_xor(rm, msk));
            float mn = fmaxf(mrow[i], rm);
            float sc = expf(mrow[i] - mn);
            mrow[i] = mn;
            float ps = 0.0f;
#pragma unroll
            for (int j = 0; j < 4; j++) {
                float p = expf(s[i][j] - mn);
                s[i][j] = p;
                ps += p;
            }
#pragma unroll
            for (int msk = 1; msk < 16; msk <<= 1)
                ps += __shfl_xor(ps, msk);
            lsum[i] = lsum[i] * sc + ps;
#pragma unroll
            for (int j = 0; j < 4; j++) o[i][j] *= sc;
        }

#pragma unroll
        for (int i = 0; i < 4; i++)
            *(float4*)&KP[ty * 4 + i][tx * 4] =
                make_float4(s[i][0], s[i][1], s[i][2], s[i][3]);
        __syncthreads();

#pragma unroll
        for (int k0 = 0; k0 < 64; k0 += 4) {
            float4 a0 = *(const float4*)&KP[ty * 4 + 0][k0];
            float4 a1 = *(const float4*)&KP[ty * 4 + 1][k0];
            float4 a2 = *(const float4*)&KP[ty * 4 + 2][k0];
            float4 a3 = *(const float4*)&KP[ty * 4 + 3][k0];
            float ar[4][4] = {{a0.x, a0.y, a0.z, a0.w},
                              {a1.x, a1.y, a1.z, a1.w},
                              {a2.x, a2.y, a2.z, a2.w},
                              {a3.x, a3.y, a3.z, a3.w}};
#pragma unroll
            for (int kk = 0; kk < 4; kk++) {
                float4 bv = *(const float4*)&Vs[k0 + kk][tx * 4];
                float br[4] = {bv.x, bv.y, bv.z, bv.w};
#pragma unroll
                for (int i = 0; i < 4; i++)
#pragma unroll
                    for (int j = 0; j < 4; j++) o[i][j] += ar[i][kk] * br[j];
            }
        }
    }

#pragma unroll
    for (int i = 0; i < 4; i++) {
        float inv = 1.0f / lsum[i];
        float4 v = make_float4(o[i][0] * inv, o[i][1] * inv,
                               o[i][2] * inv, o[i][3] * inv);
        *(float4*)(O + ((size_t)b * SEQ + qt * 64 + ty * 4 + i) * DMODEL
                   + h * DHEAD + tx * 4) = v;
    }
}

// ---------------------------------------------------------------------------
// out = LayerNorm(x + y) * g + b, one wave per row (no barriers)
// ---------------------------------------------------------------------------
__global__ __launch_bounds__(64) void ln_res_kernel(
        const float* __restrict__ x, const float* __restrict__ y,
        const float* __restrict__ g, const float* __restrict__ b,
        float* __restrict__ out) {
    int row = blockIdx.x;
    int t   = threadIdx.x;             // 0..63
    size_t base = (size_t)row * DMODEL;
    const float4* x4 = (const float4*)(x + base);
    const float4* y4 = (const float4*)(y + base);
    float4 a0 = x4[t], a1 = x4[t + 64];
    float4 c0 = y4[t], c1 = y4[t + 64];
    float v0x = a0.x + c0.x, v0y = a0.y + c0.y, v0z = a0.z + c0.z, v0w = a0.w + c0.w;
    float v1x = a1.x + c1.x, v1y = a1.y + c1.y, v1z = a1.z + c1.z, v1w = a1.w + c1.w;

    float s = v0x + v0y + v0z + v0w + v1x + v1y + v1z + v1w;
#pragma unroll
    for (int m = 1; m < 64; m <<= 1) s += __shfl_xor(s, m);
    float mu = s * (1.0f / 512.0f);

    float d0x = v0x - mu, d0y = v0y - mu, d0z = v0z - mu, d0w = v0w - mu;
    float d1x = v1x - mu, d1y = v1y - mu, d1z = v1z - mu, d1w = v1w - mu;
    float q = d0x * d0x + d0y * d0y + d0z * d0z + d0w * d0w
            + d1x * d1x + d1y * d1y + d1z * d1z + d1w * d1w;
#pragma unroll
    for (int m = 1; m < 64; m <<= 1) q += __shfl_xor(q, m);
    float inv = rsqrtf(q * (1.0f / 512.0f) + 1e-6f);

    const float4* g4 = (const float4*)g;
    const float4* b4 = (const float4*)b;
    float4 gv0 = g4[t], gv1 = g4[t + 64];
    float4 bv0 = b4[t], bv1 = b4[t + 64];
    float4* o4 = (float4*)(out + base);
    o4[t]      = make_float4(d0x * inv * gv0.x + bv0.x, d0y * inv * gv0.y + bv0.y,
                             d0z * inv * gv0.z + bv0.z, d0w * inv * gv0.w + bv0.w);
    o4[t + 64] = make_float4(d1x * inv * gv1.x + bv1.x, d1y * inv * gv1.y + bv1.y,
                             d1z * inv * gv1.z + bv1.z, d1w * inv * gv1.w + bv1.w);
}

// ---------------------------------------------------------------------------
extern "C" void kernel_launch(void* const* d_in, const int* in_sizes, int n_in,
                              void* d_out, int out_size, void* d_ws, size_t ws_size,
                              hipStream_t stream) {
    const int*   tokens = (const int*)  d_in[0];
    const float* en_out = (const float*)d_in[1];
    const float* en_pad = (const float*)d_in[2];
    const float* emb    = (const float*)d_in[3];
    const float* sa_w   = (const float*)d_in[4];
    const float* sa_b   = (const float*)d_in[5];
    const float* ca_w   = (const float*)d_in[6];
    const float* ca_b   = (const float*)d_in[7];
    const float* ff_w1  = (const float*)d_in[8];
    const float* ff_b1  = (const float*)d_in[9];
    const float* ff_w2  = (const float*)d_in[10];
    const float* ff_b2  = (const float*)d_in[11];
    const float* ln_g   = (const float*)d_in[12];
    const float* ln_b   = (const float*)d_in[13];
    const float* out_w  = (const float*)d_in[14];
    const float* out_b  = (const float*)d_in[15];
    float* logits = (float*)d_out;

    const int BS = BATCH * SEQ;               // 2048
    const size_t NTOK = (size_t)BS * DMODEL;  // 1 << 20

    float* ws   = (float*)d_ws;
    float* buf0 = ws;                 // state A
    float* buf1 = ws + NTOK;          // state B
    float* qkv  = ws + 2 * NTOK;      // fused QKV [BS][1536]
    float* kv   = qkv + NTOK;         // cross K/V view [BS][1024]
    float* att  = ws + 5 * NTOK;
    float* proj = ws + 6 * NTOK;
    float* ffb  = ws + 7 * NTOK;      // B*S*FF

    dim3 gm_qkv(BS / 128, 3 * DMODEL / 128);   // MFMA 16x12
    dim3 gm_kv(BS / 128, 2 * DMODEL / 128);    // MFMA 16x8
    dim3 gm_ff1(BS / 128, FFDIM / 128);        // MFMA 16x16
    dim3 gm_vocab(BS / 128, VOCAB / 128);      // MFMA 16x250
    dim3 g_dd(BS / 64, DMODEL / 64);           // fp32 N=512
    dim3 attn_grid(SEQ / 64, NHEAD, BATCH);

    embed_kernel<<<BS, 256, 0, stream>>>(tokens, emb, buf0);

    float* cur = buf0;
    float* oth = buf1;
    for (int l = 0; l < NLAYER; l++) {
        const float* sw = sa_w + (size_t)l * 4 * DMODEL * DMODEL;
        const float* sb = sa_b + (size_t)l * 4 * DMODEL;
        const float* cw = ca_w + (size_t)l * 4 * DMODEL * DMODEL;
        const float* cb = ca_b + (size_t)l * 4 * DMODEL;
        const float* lg = ln_g + (size_t)l * 3 * DMODEL;
        const float* lb = ln_b + (size_t)l * 3 * DMODEL;

        // ---- self-attention ----
        gemm_mfma3<<<gm_qkv, 256, 0, stream>>>(cur, sw, sb, qkv, BS, 3 * DMODEL, DMODEL, 0);
        attn_tile_kernel<<<attn_grid, 256, 0, stream>>>(qkv, qkv + DMODEL, qkv + 2 * DMODEL,
                                                        tokens, nullptr, att,
                                                        3 * DMODEL, 3 * DMODEL, 1);
        gemm_bias_64<<<g_dd, 256, 0, stream>>>(att, sw + 3 * DMODEL * DMODEL, sb + 3 * DMODEL,
                                               proj, BS, DMODEL, DMODEL, 0);
        ln_res_kernel<<<BS, 64, 0, stream>>>(cur, proj, lg, lb, oth);

        // ---- cross-attention ----
        gemm_bias_64<<<g_dd, 256, 0, stream>>>(oth, cw, cb, qkv, BS, DMODEL, DMODEL, 0);
        gemm_mfma3<<<gm_kv, 256, 0, stream>>>(en_out, cw + DMODEL * DMODEL, cb + DMODEL,
                                              kv, BS, 2 * DMODEL, DMODEL, 0);
        attn_tile_kernel<<<attn_grid, 256, 0, stream>>>(qkv, kv, kv + DMODEL,
                                                        tokens, en_pad, att,
                                                        DMODEL, 2 * DMODEL, 0);
        gemm_bias_64<<<g_dd, 256, 0, stream>>>(att, cw + 3 * DMODEL * DMODEL, cb + 3 * DMODEL,
                                               proj, BS, DMODEL, DMODEL, 0);
        ln_res_kernel<<<BS, 64, 0, stream>>>(oth, proj, lg + DMODEL, lb + DMODEL, cur);

        // ---- feed-forward ----
        gemm_mfma3<<<gm_ff1, 256, 0, stream>>>(cur, ff_w1 + (size_t)l * FFDIM * DMODEL,
                                               ff_b1 + (size_t)l * FFDIM, ffb,
                                               BS, FFDIM, DMODEL, 1);
        gemm_bias_64<<<g_dd, 256, 0, stream>>>(ffb, ff_w2 + (size_t)l * DMODEL * FFDIM,
                                               ff_b2 + (size_t)l * DMODEL, proj,
                                               BS, DMODEL, FFDIM, 0);
        ln_res_kernel<<<BS, 64, 0, stream>>>(cur, proj, lg + 2 * DMODEL, lb + 2 * DMODEL, oth);

        float* t2 = cur; cur = oth; oth = t2;
    }

    // final vocab projection
    gemm_mfma3<<<gm_vocab, 256, 0, stream>>>(cur, out_w, out_b, logits, BS, VOCAB, DMODEL, 0);
}